// Round 6
// baseline (221.369 us; speedup 1.0000x reference)
//
#include <hip/hip_runtime.h>
#include <hip/hip_bf16.h>
#include <math.h>

#define B_ 64
#define L_ 512
#define D_ 768
#define H_ 384
#define T_ 9
#define M_ (B_ * L_)   // 32768 rows

typedef __attribute__((ext_vector_type(8))) short short8;
typedef __attribute__((ext_vector_type(4))) float f32x4;

__device__ __forceinline__ unsigned short f2bf(float f) {
    unsigned u = __float_as_uint(f);
    u += 0x7FFFu + ((u >> 16) & 1u);   // RNE
    return (unsigned short)(u >> 16);
}

// packed f32x2 -> bf16x2 (v_cvt_pk_bf16_f32 on gfx950)
__device__ __forceinline__ unsigned pkbf2(float a, float b) {
    __hip_bfloat162 h = __float22bfloat162_rn(float2{a, b});
    return *(unsigned*)&h;
}

// tanh-form gelu as x * sigmoid(2*0.79788456*(x + 0.044715 x^3)) — 1 exp.
__device__ __forceinline__ float gelu_fast(float x) {
    float z2 = 1.5957691216f * x + 0.0713548162726f * x * x * x;
    return x / (1.f + __expf(-z2));
}

__device__ __forceinline__ float wredf(float v) {
#pragma unroll
    for (int m = 32; m >= 1; m >>= 1) v += __shfl_xor(v, m, 64);
    return v;
}

// LDS-only barrier: global loads stay in flight across it (no vmcnt drain).
__device__ __forceinline__ void sync_lds() {
    asm volatile("s_waitcnt lgkmcnt(0)\n\ts_barrier" ::: "memory");
}

// -----------------------------------------------------------------------------
// Kernel 0: fragment-ordered bf16 weights + zero d_out.
//   W1F[((nt*24 + kc)*64 + lane)*8 + j] = W1[kc*32 + q*8 + j][nt*16 + lm]
//   W2F[(kk*64 + lane)*8 + j]           = (lm<9) ? W2[kk*32 + q*8 + j][lm] : 0
// -----------------------------------------------------------------------------
__global__ __launch_bounds__(256) void prep_kernel(
    const float* __restrict__ W1, const float* __restrict__ W2,
    unsigned short* __restrict__ W1F, unsigned short* __restrict__ W2F,
    float* __restrict__ out)
{
    if (blockIdx.x == 0 && threadIdx.x == 0) out[0] = 0.f;
    const int g    = blockIdx.x * 4 + (threadIdx.x >> 6);
    const int lane = threadIdx.x & 63;
    const int lm   = lane & 15;
    const int q    = lane >> 4;
    if (g < 576) {                       // W1F: g = nt*24 + kc
        const int nt = g / 24;
        const int kc = g - nt * 24;
        const int n  = nt * 16 + lm;
        short8 v;
#pragma unroll
        for (int j = 0; j < 8; ++j)
            v[j] = (short)f2bf(W1[(size_t)(kc * 32 + q * 8 + j) * H_ + n]);
        *(short8*)(W1F + ((size_t)g * 64 + lane) * 8) = v;
    } else if (g < 588) {                // W2F: kk = g - 576
        const int kk = g - 576;
        short8 v;
#pragma unroll
        for (int j = 0; j < 8; ++j) {
            int k = kk * 32 + q * 8 + j;
            v[j] = (lm < 9) ? (short)f2bf(W2[(size_t)k * T_ + lm]) : (short)0;
        }
        *(short8*)(W2F + ((size_t)kk * 64 + lane) * 8) = v;
    }
}

// -----------------------------------------------------------------------------
// Kernel 1: emissions. Grid 512 row-blocks (all resident, 2 blocks/CU).
// BM=64, FULL N=384, 256 thr: wave w owns n-tiles w*6..w*6+5
// (4 m-tiles x 6 n-tiles = 24 MFMA/iter, acc[4][6]).
//
// r5 structure (bf16-in-LDS A-stage, lgkm-only barrier, verified swizzle)
// with DEEPER prefetch (r5 lesson: TLP capped at 2 waves/SIMD by acc+operand
// VGPRs, so latency hiding must come from ILP depth):
//   - X:   4 rotating named G sets  -> issued 3.8 steps ahead (~720 cy slack
//          vs ~900 cy HBM latency; residual covered by sibling-block TLP)
//   - W1F: 3 rotating named bb sets -> issued 2 steps ahead (~400 cy slack
//          vs ~200-400 cy L2 latency)
// Peak VGPR ~235 (fits the 256 cap at 2 waves/SIMD). All register indices
// literal via token-pasted macro args (rule #20).
// Sync: ONE lgkm-only barrier per k-step; vmcnt is never drained at a
// barrier (global loads are register-consumed, compiler emits counted waits).
// Epilogue: gelu -> Hs[64][392] bf16 (aliases A-bufs) -> 12 MFMA vs W2F.
// -----------------------------------------------------------------------------
__global__ __launch_bounds__(256, 2) void emis_mfma_kernel(
    const float* __restrict__ X,             // [M_][768] fp32
    const unsigned short* __restrict__ W1F,
    const float* __restrict__ b1,
    const unsigned short* __restrict__ W2F,
    const float* __restrict__ b2,
    float* __restrict__ em)                  // [M_][9] full emissions (+b2)
{
    __shared__ __align__(16) unsigned short Hs[64 * 392];  // 50176 B
    char* smem = (char*)Hs;                  // As[2][4096 B] aliases the head

    const int t    = threadIdx.x;
    const int lane = t & 63;
    const int w    = t >> 6;
    const int lm   = lane & 15;
    const int q    = lane >> 4;
    const int row0 = blockIdx.x * 64;

    // staging: thread t handles row srow = t>>2, col-chunk scb = t&3
    // (8 fp32 = 32 B global -> 16 B bf16), swizzled LDS slot.
    const int srow  = t >> 2;
    const int scb   = t & 3;
    const int sslot = scb ^ ((srow >> 1) & 3);
    const float* sp = X + (size_t)(row0 + srow) * D_ + scb * 8;
    char* swr = smem + srow * 64 + sslot * 16;       // + buf*4096

    // fragment read: row mt*16+lm, swizzled chunk q  [(row>>1)&3 == (lm>>1)&3]
    const int cq = (q ^ ((lm >> 1) & 3)) << 4;       // byte offset

    // W1F base for this wave (offsets in shorts: nt*12288 + kc*512 + lane*8)
    const unsigned short* wb = W1F + (size_t)(w * 6) * 12288 + lane * 8;

    f32x4 acc[4][6];
#pragma unroll
    for (int mt = 0; mt < 4; ++mt)
#pragma unroll
        for (int i = 0; i < 6; ++i) acc[mt][i] = (f32x4)0.f;

    short8 bb0[6], bb1[6], bb2[6];           // 3 rotating B-frag sets (2-deep)
    f32x4 gA0, gA1, gB0, gB1, gC0, gC1, gD0, gD1;  // 4 rotating X sets (3.8-deep)

#define LOADBB(dst, KC)                                                     \
    do {                                                                    \
        dst[0] = *(const short8*)(wb + 0 * 12288 + (KC) * 512);             \
        dst[1] = *(const short8*)(wb + 1 * 12288 + (KC) * 512);             \
        dst[2] = *(const short8*)(wb + 2 * 12288 + (KC) * 512);             \
        dst[3] = *(const short8*)(wb + 3 * 12288 + (KC) * 512);             \
        dst[4] = *(const short8*)(wb + 4 * 12288 + (KC) * 512);             \
        dst[5] = *(const short8*)(wb + 5 * 12288 + (KC) * 512);             \
    } while (0)

    // ---- prologue: X tiles 0..3 -> gA..gD; BB(0),BB(1); write tile0 -> buf0
    gA0 = *(const f32x4*)(sp);       gA1 = *(const f32x4*)(sp + 4);
    gB0 = *(const f32x4*)(sp + 32);  gB1 = *(const f32x4*)(sp + 36);
    gC0 = *(const f32x4*)(sp + 64);  gC1 = *(const f32x4*)(sp + 68);
    gD0 = *(const f32x4*)(sp + 96);  gD1 = *(const f32x4*)(sp + 100);
    LOADBB(bb0, 0);
    LOADBB(bb1, 1);
    {
        int4 v = {(int)pkbf2(gA0[0], gA0[1]), (int)pkbf2(gA0[2], gA0[3]),
                  (int)pkbf2(gA1[0], gA1[1]), (int)pkbf2(gA1[2], gA1[3])};
        *(int4*)(swr) = v;
    }
    sync_lds();

    // KSTEP(KC): issue G(KC+4) into Gn (the set freed last step) and
    // BB(KC+2) into BBn; MFMA tile KC from buf[KC&1] with BBc; then
    // cvt Gw (tile KC+1, loaded 3.8 steps ago) -> ds_write buf[(KC+1)&1];
    // one lgkm-only barrier.  Gn = g[KC%4], Gw = g[(KC+1)%4], BBc = bb[KC%3],
    // BBn = bb[(KC+2)%3] — all passed as named sets (literal indices).
#define KSTEP(KC, BBc, BBn, Gn0, Gn1, Gw0, Gw1)                             \
    do {                                                                    \
        if ((KC) + 4 <= 23) {                                               \
            Gn0 = *(const f32x4*)(sp + ((KC) + 4) * 32);                    \
            Gn1 = *(const f32x4*)(sp + ((KC) + 4) * 32 + 4);                \
        }                                                                   \
        if ((KC) + 2 <= 23) { LOADBB(BBn, (KC) + 2); }                      \
        {                                                                   \
            const char* fb = smem + ((KC) & 1) * 4096;                      \
            short8 af0 = *(const short8*)(fb + (0 * 16 + lm) * 64 + cq);    \
            short8 af1 = *(const short8*)(fb + (1 * 16 + lm) * 64 + cq);    \
            short8 af2 = *(const short8*)(fb + (2 * 16 + lm) * 64 + cq);    \
            short8 af3 = *(const short8*)(fb + (3 * 16 + lm) * 64 + cq);    \
            acc[0][0] = __builtin_amdgcn_mfma_f32_16x16x32_bf16(af0, BBc[0], acc[0][0], 0, 0, 0); \
            acc[0][1] = __builtin_amdgcn_mfma_f32_16x16x32_bf16(af0, BBc[1], acc[0][1], 0, 0, 0); \
            acc[0][2] = __builtin_amdgcn_mfma_f32_16x16x32_bf16(af0, BBc[2], acc[0][2], 0, 0, 0); \
            acc[0][3] = __builtin_amdgcn_mfma_f32_16x16x32_bf16(af0, BBc[3], acc[0][3], 0, 0, 0); \
            acc[0][4] = __builtin_amdgcn_mfma_f32_16x16x32_bf16(af0, BBc[4], acc[0][4], 0, 0, 0); \
            acc[0][5] = __builtin_amdgcn_mfma_f32_16x16x32_bf16(af0, BBc[5], acc[0][5], 0, 0, 0); \
            acc[1][0] = __builtin_amdgcn_mfma_f32_16x16x32_bf16(af1, BBc[0], acc[1][0], 0, 0, 0); \
            acc[1][1] = __builtin_amdgcn_mfma_f32_16x16x32_bf16(af1, BBc[1], acc[1][1], 0, 0, 0); \
            acc[1][2] = __builtin_amdgcn_mfma_f32_16x16x32_bf16(af1, BBc[2], acc[1][2], 0, 0, 0); \
            acc[1][3] = __builtin_amdgcn_mfma_f32_16x16x32_bf16(af1, BBc[3], acc[1][3], 0, 0, 0); \
            acc[1][4] = __builtin_amdgcn_mfma_f32_16x16x32_bf16(af1, BBc[4], acc[1][4], 0, 0, 0); \
            acc[1][5] = __builtin_amdgcn_mfma_f32_16x16x32_bf16(af1, BBc[5], acc[1][5], 0, 0, 0); \
            acc[2][0] = __builtin_amdgcn_mfma_f32_16x16x32_bf16(af2, BBc[0], acc[2][0], 0, 0, 0); \
            acc[2][1] = __builtin_amdgcn_mfma_f32_16x16x32_bf16(af2, BBc[1], acc[2][1], 0, 0, 0); \
            acc[2][2] = __builtin_amdgcn_mfma_f32_16x16x32_bf16(af2, BBc[2], acc[2][2], 0, 0, 0); \
            acc[2][3] = __builtin_amdgcn_mfma_f32_16x16x32_bf16(af2, BBc[3], acc[2][3], 0, 0, 0); \
            acc[2][4] = __builtin_amdgcn_mfma_f32_16x16x32_bf16(af2, BBc[4], acc[2][4], 0, 0, 0); \
            acc[2][5] = __builtin_amdgcn_mfma_f32_16x16x32_bf16(af2, BBc[5], acc[2][5], 0, 0, 0); \
            acc[3][0] = __builtin_amdgcn_mfma_f32_16x16x32_bf16(af3, BBc[0], acc[3][0], 0, 0, 0); \
            acc[3][1] = __builtin_amdgcn_mfma_f32_16x16x32_bf16(af3, BBc[1], acc[3][1], 0, 0, 0); \
            acc[3][2] = __builtin_amdgcn_mfma_f32_16x16x32_bf16(af3, BBc[2], acc[3][2], 0, 0, 0); \
            acc[3][3] = __builtin_amdgcn_mfma_f32_16x16x32_bf16(af3, BBc[3], acc[3][3], 0, 0, 0); \
            acc[3][4] = __builtin_amdgcn_mfma_f32_16x16x32_bf16(af3, BBc[4], acc[3][4], 0, 0, 0); \
            acc[3][5] = __builtin_amdgcn_mfma_f32_16x16x32_bf16(af3, BBc[5], acc[3][5], 0, 0, 0); \
        }                                                                   \
        if ((KC) + 1 <= 23) {                                               \
            int4 v = {(int)pkbf2(Gw0[0], Gw0[1]), (int)pkbf2(Gw0[2], Gw0[3]), \
                      (int)pkbf2(Gw1[0], Gw1[1]), (int)pkbf2(Gw1[2], Gw1[3])}; \
            *(int4*)(swr + (((KC) + 1) & 1) * 4096) = v;                    \
            sync_lds();                                                     \
        }                                                                   \
    } while (0)

    //      KC   BBc  BBn  Gn(=g[KC%4])  Gw(=g[(KC+1)%4])
    KSTEP(  0,  bb0, bb2, gA0, gA1, gB0, gB1);
    KSTEP(  1,  bb1, bb0, gB0, gB1, gC0, gC1);
    KSTEP(  2,  bb2, bb1, gC0, gC1, gD0, gD1);
    KSTEP(  3,  bb0, bb2, gD0, gD1, gA0, gA1);
    KSTEP(  4,  bb1, bb0, gA0, gA1, gB0, gB1);
    KSTEP(  5,  bb2, bb1, gB0, gB1, gC0, gC1);
    KSTEP(  6,  bb0, bb2, gC0, gC1, gD0, gD1);
    KSTEP(  7,  bb1, bb0, gD0, gD1, gA0, gA1);
    KSTEP(  8,  bb2, bb1, gA0, gA1, gB0, gB1);
    KSTEP(  9,  bb0, bb2, gB0, gB1, gC0, gC1);
    KSTEP( 10,  bb1, bb0, gC0, gC1, gD0, gD1);
    KSTEP( 11,  bb2, bb1, gD0, gD1, gA0, gA1);
    KSTEP( 12,  bb0, bb2, gA0, gA1, gB0, gB1);
    KSTEP( 13,  bb1, bb0, gB0, gB1, gC0, gC1);
    KSTEP( 14,  bb2, bb1, gC0, gC1, gD0, gD1);
    KSTEP( 15,  bb0, bb2, gD0, gD1, gA0, gA1);
    KSTEP( 16,  bb1, bb0, gA0, gA1, gB0, gB1);
    KSTEP( 17,  bb2, bb1, gB0, gB1, gC0, gC1);
    KSTEP( 18,  bb0, bb2, gC0, gC1, gD0, gD1);
    KSTEP( 19,  bb1, bb0, gD0, gD1, gA0, gA1);
    KSTEP( 20,  bb2, bb1, gA0, gA1, gB0, gB1);
    KSTEP( 21,  bb0, bb2, gB0, gB1, gC0, gC1);
    KSTEP( 22,  bb1, bb0, gC0, gC1, gD0, gD1);
    KSTEP( 23,  bb2, bb1, gD0, gD1, gA0, gA1);

#undef KSTEP
#undef LOADBB

    __syncthreads();   // all ds_reads done before Hs (alias) is written

    // ---- epilogue A: +b1, gelu -> Hs[64][392] (full 384 cols) ----
#pragma unroll
    for (int i = 0; i < 6; ++i) {
        const int lc = w * 96 + i * 16 + lm;
        const float b1v = b1[lc];
#pragma unroll
        for (int mt = 0; mt < 4; ++mt)
#pragma unroll
            for (int r = 0; r < 4; ++r) {
                float h = gelu_fast(acc[mt][i][r] + b1v);
                Hs[(mt * 16 + q * 4 + r) * 392 + lc] = f2bf(h);
            }
    }
    __syncthreads();

    // ---- epilogue B: em = h @ W2 via 12 MFMA, +b2, single buffer ----
    f32x4 e = (f32x4)0.f;
#pragma unroll
    for (int kk = 0; kk < 12; ++kk) {
        short8 ah = *(const short8*)&Hs[(w * 16 + lm) * 392 + kk * 32 + (q << 3)];
        short8 bw = *(const short8*)(W2F + ((size_t)(kk * 64 + lane)) * 8);
        e = __builtin_amdgcn_mfma_f32_16x16x32_bf16(ah, bw, e, 0, 0, 0);
    }
    if (lm < 9) {
#pragma unroll
        for (int r = 0; r < 4; ++r)
            em[(size_t)(row0 + w * 16 + q * 4 + r) * T_ + lm] = e[r] + b2[lm];
    }
}

// -----------------------------------------------------------------------------
// Kernel 2: CRF. 64 blocks x 640 threads. (Single em input.)
// Phase A: threads 0..575 = (chunk c, row i0) build 9x9 transfer matrices;
// wave 9 computes the numerator concurrently. Phase B: 6-level tree combine.
// Final: alpha0 x M_total, logsumexp, atomicAdd (denom-numer)/B.
// -----------------------------------------------------------------------------
__global__ __launch_bounds__(640) void crf_kernel(
    const float* __restrict__ em,
    const int* __restrict__ labels,
    const unsigned char* __restrict__ maskb,
    const float* __restrict__ st,
    const float* __restrict__ et,
    const float* __restrict__ tr,
    float* __restrict__ out)
{
    const int b = blockIdx.x;
    const int t = threadIdx.x;

    __shared__ float es[64 * 73];    // es[c*73 + s*9 + j]
    __shared__ float Msa[64 * 81];
    __shared__ float Msb[32 * 81];
    __shared__ float trs[81];
    __shared__ float red_num;
    __shared__ unsigned char msh[L_];
    __shared__ int lbs[L_];

    const int mstride =
        (maskb[0] != 0 && maskb[1] == 0 && maskb[2] == 0 && maskb[3] == 0) ? 4 : 1;

    const float* e0 = em + (size_t)b * L_ * T_;
    for (int i = t; i < L_ * T_; i += 640) {
        int tt = i / T_, j = i - tt * T_;
        es[(tt >> 3) * 73 + (tt & 7) * 9 + j] = e0[i];
    }
    if (t < 81) trs[t] = tr[t];
    for (int i = t; i < L_; i += 640) {
        msh[i] = maskb[((size_t)b * L_ + i) * (size_t)mstride];
        lbs[i] = labels[b * L_ + i];
    }
    __syncthreads();

    if (t < 576) {
        // ---- Phase A ----
        const int c  = t / 9;
        const int i0 = t - c * 9;
        float trr[81];
#pragma unroll
        for (int i = 0; i < 81; ++i) trr[i] = trs[i];
        float V[9];
#pragma unroll
        for (int j = 0; j < 9; ++j) V[j] = (j == i0) ? 0.f : -1e30f;

        const int sbeg = (c == 0) ? 1 : 0;
        for (int s = sbeg; s < 8; ++s) {
            int tt = c * 8 + s;
            if (msh[tt]) {
                const float* ep = &es[c * 73 + s * 9];
                float nv[9];
#pragma unroll
                for (int j = 0; j < 9; ++j) {
                    float a[9];
#pragma unroll
                    for (int k = 0; k < 9; ++k) a[k] = V[k] + trr[k * 9 + j];
                    float mx = a[0];
#pragma unroll
                    for (int k = 1; k < 9; ++k) mx = fmaxf(mx, a[k]);
                    float sum = 0.f;
#pragma unroll
                    for (int k = 0; k < 9; ++k) sum += __expf(a[k] - mx);
                    nv[j] = ep[j] + mx + __logf(sum);
                }
#pragma unroll
                for (int j = 0; j < 9; ++j) V[j] = nv[j];
            }
        }
#pragma unroll
        for (int j = 0; j < 9; ++j) Msa[c * 81 + i0 * 9 + j] = V[j];
    } else {
        // ---- numerator (wave 9, concurrent with Phase A) ----
        const int lane = t - 576;
        float emit_s = 0.f, tr_sc = 0.f, mcnt = 0.f;
        for (int tt = lane; tt < L_; tt += 64) {
            if (msh[tt]) {
                mcnt += 1.f;
                int tag = lbs[tt];
                emit_s += es[(tt >> 3) * 73 + (tt & 7) * 9 + tag];
                if (tt >= 1) tr_sc += trs[lbs[tt - 1] * 9 + tag];
            }
        }
        emit_s = wredf(emit_s);
        tr_sc  = wredf(tr_sc);
        mcnt   = wredf(mcnt);
        if (lane == 0) {
            int last = (int)mcnt - 1;
            red_num = st[lbs[0]] + emit_s + tr_sc + et[lbs[last]];
        }
    }
    __syncthreads();

    // ---- Phase B: tree combine, 6 levels ----
    float* src = Msa;
    float* dst = Msb;
    for (int n = 32; n >= 1; n >>= 1) {
        for (int idx = t; idx < n * 81; idx += 640) {
            int p = idx / 81;
            int r = idx - p * 81;
            int i = r / 9, j = r - i * 9;
            const float* A  = src + (2 * p) * 81 + i * 9;
            const float* Bm = src + (2 * p + 1) * 81 + j;
            float v[9];
#pragma unroll
            for (int k = 0; k < 9; ++k) v[k] = A[k] + Bm[k * 9];
            float mx = v[0];
#pragma unroll
            for (int k = 1; k < 9; ++k) mx = fmaxf(mx, v[k]);
            float sum = 0.f;
#pragma unroll
            for (int k = 0; k < 9; ++k) sum += __expf(v[k] - mx);
            dst[p * 81 + r] = mx + __logf(sum);
        }
        __syncthreads();
        float* tmp = src; src = dst; dst = tmp;
    }
    // final matrix in src (= Msa after 6 swaps)

    if (t < 64) {
        float v = -3.0e38f;
        if (t < 9) {
            float a[9];
#pragma unroll
            for (int i = 0; i < 9; ++i) a[i] = st[i] + es[i] + src[i * 9 + t];
            float mx = a[0];
#pragma unroll
            for (int i = 1; i < 9; ++i) mx = fmaxf(mx, a[i]);
            float sum = 0.f;
#pragma unroll
            for (int i = 0; i < 9; ++i) sum += __expf(a[i] - mx);
            v = mx + __logf(sum) + et[t];
        }
        float mx = v;
#pragma unroll
        for (int m = 32; m >= 1; m >>= 1) mx = fmaxf(mx, __shfl_xor(mx, m, 64));
        float sm = __expf(v - mx);
        sm = wredf(sm);
        if (t == 0) {
            float denom = mx + __logf(sm);
            atomicAdd(out, (denom - red_num) * (1.0f / (float)B_));
        }
    }
}

extern "C" void kernel_launch(void* const* d_in, const int* in_sizes, int n_in,
                              void* d_out, int out_size, void* d_ws, size_t ws_size,
                              hipStream_t stream) {
    const float*         enc    = (const float*)d_in[0];
    const int*           labels = (const int*)d_in[1];
    const unsigned char* mask   = (const unsigned char*)d_in[2];
    const float*         W1     = (const float*)d_in[3];
    const float*         b1     = (const float*)d_in[4];
    const float*         W2     = (const float*)d_in[5];
    const float*         b2     = (const float*)d_in[6];
    const float*         st     = (const float*)d_in[7];
    const float*         et     = (const float*)d_in[8];
    const float*         tr     = (const float*)d_in[9];

    float* em           = (float*)d_ws;                        // 1,179,648 B
    unsigned short* W1F = (unsigned short*)(em + (size_t)M_ * T_);   // 589,824 B
    unsigned short* W2F = W1F + (size_t)576 * 64 * 8;          // 12,288 B

    prep_kernel<<<147, 256, 0, stream>>>(W1, W2, W1F, W2F, (float*)d_out);
    emis_mfma_kernel<<<512, 256, 0, stream>>>(enc, W1F, b1, W2F, b2, em);
    crf_kernel<<<B_, 640, 0, stream>>>(em, labels, mask, st, et, tr, (float*)d_out);
}